// Round 8
// baseline (602.522 us; speedup 1.0000x reference)
//
#include <hip/hip_runtime.h>

#define NZ 81
#define OBS_DIM 48
#define MAX_ADJ 5
#define NTASK (NZ * MAX_ADJ)       // 405
#define TPAD 408
#define NEG_INF -1000000000.0f
#define BLOCK 512
#define ROWS 16                    // batch rows per block
#define GROUP 4                    // rows per pipeline group
#define NGRP (ROWS / GROUP)        // 4
#define ROW_DW (NZ * NZ)           // 6561 dwords per output row
#define GRP_F4 ((GROUP * ROW_DW) / 4)   // 6561 float4 per group (exact)
#define BLK_F4 ((ROWS * ROW_DW) / 4)    // 26244 float4 per block (16B-aligned base)

__global__ __launch_bounds__(BLOCK) void taxi_actor_kernel(
    const float* __restrict__ obs,   // [B, 48]
    const float* __restrict__ W,     // [81, 48, 5]
    const float* __restrict__ bias,  // [81, 5]
    const int*   __restrict__ idx,   // [81, 5]
    const float* __restrict__ mask,  // [81, 5]
    float* __restrict__ out)         // [B, 81, 81]
{
    __shared__ float s_obs[ROWS * OBS_DIM];    // 3 KB
    __shared__ float s_lp[2][GROUP][TPAD];     // 13 KB, double-buffered probs
    __shared__ int   s_idx[NTASK];             // 1.6 KB
    __shared__ short s_map[ROW_DW + 2];        // 13.1 KB: position -> task (-1 = zero)

    const int tid = threadIdx.x;
    const size_t b0 = (size_t)blockIdx.x * ROWS;

    // Stage obs (vectorized) + adjacency.
    if (tid < ROWS * OBS_DIM / 4) {
        const float4* src = reinterpret_cast<const float4*>(obs + b0 * OBS_DIM);
        reinterpret_cast<float4*>(s_obs)[tid] = src[tid];
    }
    if (tid < NTASK)
        s_idx[tid] = (mask[tid] > 0.0f) ? idx[tid] : -1;
    __syncthreads();

    // Build position->task map once per block (reused by all 4 store phases).
    for (int p = tid; p < ROW_DW; p += BLOCK) {
        const int n = p / NZ;
        const int z = p - n * NZ;
        short t = -1;
        #pragma unroll
        for (int k = 0; k < MAX_ADJ; ++k)
            if (s_idx[n * MAX_ADJ + k] == z) t = (short)(n * MAX_ADJ + k);
        s_map[p] = t;
    }

    // Per-task constants.
    const float* __restrict__ Wp = W;
    float bv = 0.0f;
    bool valid = false;
    if (tid < NTASK) {
        const int n = tid / MAX_ADJ;
        const int k = tid - n * MAX_ADJ;
        Wp = W + n * (OBS_DIM * MAX_ADJ) + k;
        bv = bias[tid];
        valid = (mask[tid] > 0.0f);
    }

    // ---- group phases -------------------------------------------------
    auto compute_group = [&](int g) {
        if (tid < NTASK) {
            float a0 = 0.f, a1 = 0.f, a2 = 0.f, a3 = 0.f;
            const int rb = g * GROUP;
            #pragma unroll
            for (int d4 = 0; d4 < OBS_DIM; d4 += 4) {
                const float w0 = Wp[(d4 + 0) * MAX_ADJ];
                const float w1 = Wp[(d4 + 1) * MAX_ADJ];
                const float w2 = Wp[(d4 + 2) * MAX_ADJ];
                const float w3 = Wp[(d4 + 3) * MAX_ADJ];
                const float4 o0 = *reinterpret_cast<const float4*>(&s_obs[(rb + 0) * OBS_DIM + d4]);
                const float4 o1 = *reinterpret_cast<const float4*>(&s_obs[(rb + 1) * OBS_DIM + d4]);
                const float4 o2 = *reinterpret_cast<const float4*>(&s_obs[(rb + 2) * OBS_DIM + d4]);
                const float4 o3 = *reinterpret_cast<const float4*>(&s_obs[(rb + 3) * OBS_DIM + d4]);
                a0 = fmaf(o0.x, w0, a0); a0 = fmaf(o0.y, w1, a0); a0 = fmaf(o0.z, w2, a0); a0 = fmaf(o0.w, w3, a0);
                a1 = fmaf(o1.x, w0, a1); a1 = fmaf(o1.y, w1, a1); a1 = fmaf(o1.z, w2, a1); a1 = fmaf(o1.w, w3, a1);
                a2 = fmaf(o2.x, w0, a2); a2 = fmaf(o2.y, w1, a2); a2 = fmaf(o2.z, w2, a2); a2 = fmaf(o2.w, w3, a2);
                a3 = fmaf(o3.x, w0, a3); a3 = fmaf(o3.y, w1, a3); a3 = fmaf(o3.z, w2, a3); a3 = fmaf(o3.w, w3, a3);
            }
            const int cur = g & 1;
            s_lp[cur][0][tid] = valid ? (a0 + bv) : NEG_INF;
            s_lp[cur][1][tid] = valid ? (a1 + bv) : NEG_INF;
            s_lp[cur][2][tid] = valid ? (a2 + bv) : NEG_INF;
            s_lp[cur][3][tid] = valid ? (a3 + bv) : NEG_INF;
        }
    };

    auto softmax_group = [&](int g) {
        if (tid < GROUP * NZ) {               // 324 tasks
            const int cur = g & 1;
            const int r = tid / NZ;
            const int n = tid - r * NZ;
            float l[MAX_ADJ];
            float m = NEG_INF;
            #pragma unroll
            for (int k = 0; k < MAX_ADJ; ++k) {
                l[k] = s_lp[cur][r][n * MAX_ADJ + k];
                m = fmaxf(m, l[k]);
            }
            float ssum = 0.0f;
            #pragma unroll
            for (int k = 0; k < MAX_ADJ; ++k) {
                l[k] = __expf(l[k] - m);      // masked: exp(-1e9) -> 0
                ssum += l[k];
            }
            const float inv = 1.0f / ssum;
            #pragma unroll
            for (int k = 0; k < MAX_ADJ; ++k)
                s_lp[cur][r][n * MAX_ADJ + k] = l[k] * inv;
        }
    };

    auto store_group = [&](int g) {
        const int cur = g & 1;
        float4* __restrict__ ob =
            reinterpret_cast<float4*>(out) + (size_t)blockIdx.x * BLK_F4 + (size_t)g * GRP_F4;
        int q   = tid;          // float4 index within group
        int rg  = 0;            // row within group  (= 4q / 6561)
        int pos = 4 * tid;      // dword pos in row  (= 4q % 6561)
        for (int i = 0; i < 13; ++i) {
            if (q < GRP_F4) {
                float vv[4];
                #pragma unroll
                for (int j = 0; j < 4; ++j) {
                    int pj = pos + j;
                    int rj = rg;
                    if (pj >= ROW_DW) { pj -= ROW_DW; ++rj; }
                    const short t = s_map[pj];
                    float val = 0.0f;
                    if (t >= 0) val = s_lp[cur][rj][t];
                    vv[j] = val;
                }
                ob[q] = make_float4(vv[0], vv[1], vv[2], vv[3]);
            }
            q += BLOCK;
            pos += 4 * BLOCK;
            if (pos >= ROW_DW) { pos -= ROW_DW; ++rg; }
        }
    };

    // ---- software pipeline: stores of group g drain under compute g+1 --
    compute_group(0);
    for (int g = 0; g < NGRP; ++g) {
        __syncthreads();          // compute g complete
        softmax_group(g);
        __syncthreads();          // probs visible
        store_group(g);           // posted stores, fire-and-forget
        if (g + 1 < NGRP)
            compute_group(g + 1); // overlaps store drain
    }
}

extern "C" void kernel_launch(void* const* d_in, const int* in_sizes, int n_in,
                              void* d_out, int out_size, void* d_ws, size_t ws_size,
                              hipStream_t stream) {
    const float* obs  = (const float*)d_in[0];
    const float* W    = (const float*)d_in[1];
    const float* bias = (const float*)d_in[2];
    const int*   idx  = (const int*)d_in[3];
    const float* mask = (const float*)d_in[4];
    float* out = (float*)d_out;

    const int B = in_sizes[0] / OBS_DIM;   // 32768, divisible by ROWS
    taxi_actor_kernel<<<B / ROWS, BLOCK, 0, stream>>>(obs, W, bias, idx, mask, out);
}

// Round 9
// 221.192 us; speedup vs baseline: 2.7240x; 2.7240x over previous
//
#include <hip/hip_runtime.h>

#define NZ 81
#define OBS_DIM 48
#define MAX_ADJ 5
#define NTASK (NZ * MAX_ADJ)   // 405
#define TPAD 408
#define NEG_INF -1000000000.0f
#define BLOCK 512
#define ROWS 16                // batch rows per block
#define CHUNK 4                // rows per compute chunk (acc[4])
#define NCHUNK (ROWS / CHUNK)  // 4
#define ROW_DW (NZ * NZ)       // 6561
#define NPOS 13                // ceil(6561/512) output dwords per thread per row

__global__ __launch_bounds__(BLOCK) void taxi_actor_kernel(
    const float* __restrict__ obs,   // [B, 48]
    const float* __restrict__ W,     // [81, 48, 5]
    const float* __restrict__ bias,  // [81, 5]
    const int*   __restrict__ idx,   // [81, 5]
    const float* __restrict__ mask,  // [81, 5]
    float* __restrict__ out)         // [B, 81, 81]
{
    __shared__ float s_obs[ROWS * OBS_DIM];   // 3 KB
    __shared__ float s_lp[CHUNK][TPAD];       // 6.5 KB: logits -> probs in place
    __shared__ int   s_idx[NTASK];            // 1.6 KB (masked -> -1)

    const int tid = threadIdx.x;
    const size_t b0 = (size_t)blockIdx.x * ROWS;

    // Stage obs rows (vectorized, coalesced) + adjacency.
    if (tid < ROWS * OBS_DIM / 4) {
        const float4* src = reinterpret_cast<const float4*>(obs + b0 * OBS_DIM);
        reinterpret_cast<float4*>(s_obs)[tid] = src[tid];
    }
    if (tid < NTASK)
        s_idx[tid] = (mask[tid] > 0.0f) ? idx[tid] : -1;
    __syncthreads();

    // Register inverse map: output dword p=tid+i*BLOCK -> feeding task (-1 => 0).
    // Fully unrolled so tmap[] stays in VGPRs.
    int tmap[NPOS];
    #pragma unroll
    for (int i = 0; i < NPOS; ++i) {
        tmap[i] = -1;
        const int p = tid + i * BLOCK;
        if (p < ROW_DW) {
            const int n = p / NZ;
            const int z = p - n * NZ;
            #pragma unroll
            for (int k = 0; k < MAX_ADJ; ++k)
                if (s_idx[n * MAX_ADJ + k] == z) tmap[i] = n * MAX_ADJ + k;
        }
    }

    // Per-task constants.
    const float* __restrict__ Wp = W;
    float bv = 0.0f;
    bool valid = false;
    const int n0 = tid / MAX_ADJ;
    const int k0 = tid - n0 * MAX_ADJ;
    if (tid < NTASK) {
        Wp = W + n0 * (OBS_DIM * MAX_ADJ) + k0;
        bv = bias[tid];
        valid = (s_idx[tid] >= 0);
    }

    for (int c = 0; c < NCHUNK; ++c) {
        const int rb = c * CHUNK;

        // Compute chunk: 4-row batched dot. W element loaded once -> 4 FMAs.
        // (Runs BEFORE the barrier so it overlaps the drain of chunk c-1's
        // posted stores; the barrier's vmcnt(0) is then nearly free.)
        float a0 = 0.f, a1 = 0.f, a2 = 0.f, a3 = 0.f;
        if (tid < NTASK) {
            #pragma unroll
            for (int d4 = 0; d4 < OBS_DIM; d4 += 4) {
                const float w0 = Wp[(d4 + 0) * MAX_ADJ];
                const float w1 = Wp[(d4 + 1) * MAX_ADJ];
                const float w2 = Wp[(d4 + 2) * MAX_ADJ];
                const float w3 = Wp[(d4 + 3) * MAX_ADJ];
                const float4 o0 = *reinterpret_cast<const float4*>(&s_obs[(rb + 0) * OBS_DIM + d4]);
                const float4 o1 = *reinterpret_cast<const float4*>(&s_obs[(rb + 1) * OBS_DIM + d4]);
                const float4 o2 = *reinterpret_cast<const float4*>(&s_obs[(rb + 2) * OBS_DIM + d4]);
                const float4 o3 = *reinterpret_cast<const float4*>(&s_obs[(rb + 3) * OBS_DIM + d4]);
                a0 = fmaf(o0.x, w0, a0); a0 = fmaf(o0.y, w1, a0); a0 = fmaf(o0.z, w2, a0); a0 = fmaf(o0.w, w3, a0);
                a1 = fmaf(o1.x, w0, a1); a1 = fmaf(o1.y, w1, a1); a1 = fmaf(o1.z, w2, a1); a1 = fmaf(o1.w, w3, a1);
                a2 = fmaf(o2.x, w0, a2); a2 = fmaf(o2.y, w1, a2); a2 = fmaf(o2.z, w2, a2); a2 = fmaf(o2.w, w3, a2);
                a3 = fmaf(o3.x, w0, a3); a3 = fmaf(o3.y, w1, a3); a3 = fmaf(o3.z, w2, a3); a3 = fmaf(o3.w, w3, a3);
            }
        }
        __syncthreads();   // chunk c-1's store phase done reading s_lp
        if (tid < NTASK) {
            s_lp[0][tid] = valid ? (a0 + bv) : NEG_INF;
            s_lp[1][tid] = valid ? (a1 + bv) : NEG_INF;
            s_lp[2][tid] = valid ? (a2 + bv) : NEG_INF;
            s_lp[3][tid] = valid ? (a3 + bv) : NEG_INF;
        }
        __syncthreads();   // logits visible

        // Softmax in place: 4*81 = 324 (row, zone) tasks.
        if (tid < CHUNK * NZ) {
            const int r = tid / NZ;
            const int n = tid - r * NZ;
            float l[MAX_ADJ];
            float m = NEG_INF;
            #pragma unroll
            for (int k = 0; k < MAX_ADJ; ++k) {
                l[k] = s_lp[r][n * MAX_ADJ + k];
                m = fmaxf(m, l[k]);
            }
            float ssum = 0.0f;
            #pragma unroll
            for (int k = 0; k < MAX_ADJ; ++k) {
                l[k] = __expf(l[k] - m);   // masked: exp(-1e9) -> 0
                ssum += l[k];
            }
            const float inv = 1.0f / ssum;
            #pragma unroll
            for (int k = 0; k < MAX_ADJ; ++k)
                s_lp[r][n * MAX_ADJ + k] = l[k] * inv;
        }
        __syncthreads();   // probs ready

        // Store 4 rows: plain coalesced dword stores (proven exact-byte
        // pattern), ~94% immediate zeros. Posted; drain hides under the
        // next chunk's FMA loop.
        #pragma unroll
        for (int r = 0; r < CHUNK; ++r) {
            float* __restrict__ ob = out + (b0 + rb + r) * (size_t)ROW_DW;
            #pragma unroll
            for (int i = 0; i < NPOS; ++i) {
                const int p = tid + i * BLOCK;
                if (p < ROW_DW)
                    ob[p] = (tmap[i] >= 0) ? s_lp[r][tmap[i]] : 0.0f;
            }
        }
    }
}

extern "C" void kernel_launch(void* const* d_in, const int* in_sizes, int n_in,
                              void* d_out, int out_size, void* d_ws, size_t ws_size,
                              hipStream_t stream) {
    const float* obs  = (const float*)d_in[0];
    const float* W    = (const float*)d_in[1];
    const float* bias = (const float*)d_in[2];
    const int*   idx  = (const int*)d_in[3];
    const float* mask = (const float*)d_in[4];
    float* out = (float*)d_out;

    const int B = in_sizes[0] / OBS_DIM;   // 32768, divisible by ROWS
    taxi_actor_kernel<<<B / ROWS, BLOCK, 0, stream>>>(obs, W, bias, idx, mask, out);
}